// Round 8
// baseline (262.165 us; speedup 1.0000x reference)
//
#include <hip/hip_runtime.h>

typedef __attribute__((ext_vector_type(8))) short s16x8;   // 8 bf16
typedef __attribute__((ext_vector_type(4))) float f32x4;
typedef __attribute__((ext_vector_type(4))) int   i32x4;

#define HID 512
#define NROWS 8192
#define TAU_INV 1.25f

__device__ __forceinline__ float bf2f(short s) {
    union { unsigned u; float f; } v;
    v.u = ((unsigned)(unsigned short)s) << 16;
    return v.f;
}
__device__ __forceinline__ short f2bf(float f) {
    unsigned u = __float_as_uint(f);
    u += 0x7fffu + ((u >> 16) & 1u);   // round-to-nearest-even
    return (short)(u >> 16);
}

__device__ __forceinline__ void gload_lds16(const void* g, void* l) {
    __builtin_amdgcn_global_load_lds(
        (const __attribute__((address_space(1))) unsigned int*)g,
        (__attribute__((address_space(3))) unsigned int*)l, 16, 0, 0);
}

__device__ __forceinline__ int dot4i(int a, int b) {
    int s = 0;
#pragma unroll
    for (int i = 0; i < 4; ++i)
        s += (int)(signed char)(a >> (8 * i)) * (int)(signed char)(b >> (8 * i));
    return s;
}

// ---------------------------------------------------------------------------
// Fused fp32->bf16 convert for z_mp, z_sc, W1, W2 in one launch.
// ---------------------------------------------------------------------------
__global__ void convert_all(const float* __restrict__ z1, const float* __restrict__ z2,
                            const float* __restrict__ w1, const float* __restrict__ w2,
                            short* __restrict__ Zb1, short* __restrict__ Zb2,
                            short* __restrict__ Wb1, short* __restrict__ Wb2)
{
    const int ZN = NROWS * HID, WN = HID * HID;
    long i = (long)(blockIdx.x * blockDim.x + threadIdx.x) * 4;
    const float* src;
    short* dst;
    long off;
    if (i < ZN)                { src = z1; dst = Zb1; off = i; }
    else if (i < 2L * ZN)      { src = z2; dst = Zb2; off = i - ZN; }
    else if (i < 2L * ZN + WN) { src = w1; dst = Wb1; off = i - 2L * ZN; }
    else                       { src = w2; dst = Wb2; off = i - 2L * ZN - WN; }
    float4 v = *(const float4*)(src + off);
    short4 o;
    o.x = f2bf(v.x); o.y = f2bf(v.y); o.z = f2bf(v.z); o.w = f2bf(v.w);
    *(short4*)(dst + off) = o;
}

// ---------------------------------------------------------------------------
// bf16 NT GEMM — R2 structure verbatim (verified fastest of 5 variants):
// 128x128 tile, BK=32, row-major LDS (32-short rows), 4 waves of 64x64.
// ---------------------------------------------------------------------------
__global__ __launch_bounds__(256, 2)
void gemm_proj(const short* __restrict__ A0, const short* __restrict__ A1,
               const short* __restrict__ B, const float* __restrict__ bias,
               short* __restrict__ C0, short* __restrict__ C1, int do_elu)
{
    __shared__ short ldsA[128 * 32];
    __shared__ short ldsB[128 * 32];
    const short* A = blockIdx.z ? A1 : A0;
    short* C = blockIdx.z ? C1 : C0;
    const int tid = threadIdx.x;
    const int w = tid >> 6, lane = tid & 63;
    const int wm = w >> 1, wn = w & 1;
    const int quad = lane >> 4, r16 = lane & 15;
    const int bM = blockIdx.x * 128, bN = blockIdx.y * 128;
    const int lrow = lane >> 2, lcol = (lane & 3) * 8;

    f32x4 acc[4][4] = {};

    for (int k0 = 0; k0 < HID; k0 += 32) {
        __syncthreads();
#pragma unroll
        for (int i = 0; i < 2; ++i) {
            int r0 = (w * 2 + i) * 16;
            gload_lds16(A + (size_t)(bM + r0 + lrow) * HID + k0 + lcol, &ldsA[r0 * 32]);
            gload_lds16(B + (size_t)(bN + r0 + lrow) * HID + k0 + lcol, &ldsB[r0 * 32]);
        }
        __syncthreads();
        s16x8 af[4], bfr[4];
#pragma unroll
        for (int t = 0; t < 4; ++t) {
            af[t]  = *(const s16x8*)&ldsA[(wm * 64 + t * 16 + r16) * 32 + quad * 8];
            bfr[t] = *(const s16x8*)&ldsB[(wn * 64 + t * 16 + r16) * 32 + quad * 8];
        }
#pragma unroll
        for (int tm = 0; tm < 4; ++tm)
#pragma unroll
            for (int tn = 0; tn < 4; ++tn)
                acc[tm][tn] = __builtin_amdgcn_mfma_f32_16x16x32_bf16(
                    af[tm], bfr[tn], acc[tm][tn], 0, 0, 0);
    }

#pragma unroll
    for (int tn = 0; tn < 4; ++tn) {
        int gcol = bN + wn * 64 + tn * 16 + r16;
        float bv = bias[gcol];
#pragma unroll
        for (int tm = 0; tm < 4; ++tm) {
#pragma unroll
            for (int r = 0; r < 4; ++r) {
                int grow = bM + wm * 64 + tm * 16 + quad * 4 + r;  // C/D: row=(lane>>4)*4+reg
                float v = acc[tm][tn][r] + bv;
                if (do_elu) v = v > 0.f ? v : __expf(v) - 1.f;
                C[(size_t)grow * HID + gcol] = f2bf(v);
            }
        }
    }
}

// ---------------------------------------------------------------------------
// normalize + int8 row-quantize: q = round(n * 127/max|n_row|), one wave/row.
// recip[row] = max|n_row|/127, so dot_real = i32acc * recip[r] * recip[c].
// ---------------------------------------------------------------------------
__global__ void normalize_quant(const short* __restrict__ P, char* __restrict__ Q,
                                float* __restrict__ recip, int nrows)
{
    int gt = blockIdx.x * blockDim.x + threadIdx.x;
    int row = gt >> 6, lane = gt & 63;
    if (row >= nrows) return;
    const short* p = P + (size_t)row * HID + lane * 8;
    s16x8 v = *(const s16x8*)p;
    float f[8], ss = 0.f, am = 0.f;
#pragma unroll
    for (int i = 0; i < 8; ++i) {
        f[i] = bf2f(v[i]);
        ss += f[i] * f[i];
        am = fmaxf(am, fabsf(f[i]));
    }
#pragma unroll
    for (int m = 1; m < 64; m <<= 1) {
        ss += __shfl_xor(ss, m, 64);
        am = fmaxf(am, __shfl_xor(am, m, 64));
    }
    float inv = rsqrtf(ss);
    float maxn = am * inv;             // max |n_i| over the row
    float s = 127.f / maxn;
    int lo = 0, hi = 0;
#pragma unroll
    for (int i = 0; i < 4; ++i) {
        int q0 = (int)lrintf(f[i] * inv * s);
        int q1 = (int)lrintf(f[i + 4] * inv * s);
        lo |= (q0 & 255) << (8 * i);
        hi |= (q1 & 255) << (8 * i);
    }
    ((int2*)(Q + (size_t)row * HID))[lane] = make_int2(lo, hi);
    if (lane == 0) recip[row] = maxn * (1.f / 127.f);
}

// ---------------------------------------------------------------------------
// int8 similarity with XCD-aware swizzle: flat 4096-block grid; block b lands
// on XCD b%8 (HW round-robin). Map b so XCD X owns col tiles [8X, 8X+8)
// (512 KB of Q2, L2-resident) and streams row tiles with 8x consecutive
// reuse (64 KB hot) -> staging drains hit L2 (~200cy) instead of HBM (~900cy).
// ---------------------------------------------------------------------------
__global__ __launch_bounds__(256, 4)
void gemm_sim(const char* __restrict__ Q1, const char* __restrict__ Q2,
              const float* __restrict__ recip,
              float* __restrict__ rowsum, float* __restrict__ colsum)
{
    __shared__ char ldsA[128 * 64];
    __shared__ char ldsB[128 * 64];
    const int tid = threadIdx.x;
    const int w = tid >> 6, lane = tid & 63;
    const int wm = w >> 1, wn = w & 1;
    const int quad = lane >> 4, r16 = lane & 15;
    const int b = blockIdx.x;
    const int xcd = b & 7, q = b >> 3;
    const int bM = (q >> 3) * 128;                 // row tile: 8x consecutive reuse per XCD
    const int bN = (xcd * 8 + (q & 7)) * 128;      // col slice owned by this XCD
    const int lrow = lane >> 2, lcol = (lane & 3) * 16;   // bytes within 64B row

    i32x4 acc[4][4] = {};

    for (int k0 = 0; k0 < HID; k0 += 64) {
        __syncthreads();
#pragma unroll
        for (int i = 0; i < 2; ++i) {
            int r0 = (w * 2 + i) * 16;
            gload_lds16(Q1 + (size_t)(bM + r0 + lrow) * HID + k0 + lcol, &ldsA[r0 * 64]);
            gload_lds16(Q2 + (size_t)(bN + r0 + lrow) * HID + k0 + lcol, &ldsB[r0 * 64]);
        }
        __syncthreads();
        i32x4 af[4], bfr[4];
#pragma unroll
        for (int t = 0; t < 4; ++t) {
            af[t]  = *(const i32x4*)&ldsA[(wm * 64 + t * 16 + r16) * 64 + quad * 16];
            bfr[t] = *(const i32x4*)&ldsB[(wn * 64 + t * 16 + r16) * 64 + quad * 16];
        }
#pragma unroll
        for (int tm = 0; tm < 4; ++tm)
#pragma unroll
            for (int tn = 0; tn < 4; ++tn)
                acc[tm][tn] = __builtin_amdgcn_mfma_i32_16x16x64_i8(
                    af[tm], bfr[tn], acc[tm][tn], 0, 0, 0);
    }

    // epilogue: scale, exp, reduce. cb folds in TAU_INV.
    float cb[4], cs[4] = {0.f, 0.f, 0.f, 0.f};
#pragma unroll
    for (int tn = 0; tn < 4; ++tn)
        cb[tn] = recip[NROWS + bN + wn * 64 + tn * 16 + r16] * TAU_INV;

#pragma unroll
    for (int tm = 0; tm < 4; ++tm) {
#pragma unroll
        for (int r = 0; r < 4; ++r) {
            int grow = bM + wm * 64 + tm * 16 + quad * 4 + r;  // C/D: row=quad*4+reg
            float ra = recip[grow];
            float rs = 0.f;
#pragma unroll
            for (int tn = 0; tn < 4; ++tn) {
                float e = __expf((float)acc[tm][tn][r] * ra * cb[tn]);
                rs += e;
                cs[tn] += e;
            }
#pragma unroll
            for (int m = 1; m < 16; m <<= 1) rs += __shfl_xor(rs, m, 64);
            if (r16 == 0) atomicAdd(&rowsum[grow], rs);
        }
    }
#pragma unroll
    for (int tn = 0; tn < 4; ++tn) {
        float c = cs[tn];
        c += __shfl_xor(c, 16, 64);
        c += __shfl_xor(c, 32, 64);
        if (quad == 0)
            atomicAdd(&colsum[bN + wn * 64 + tn * 16 + r16], c);
    }
}

// ---------------------------------------------------------------------------
// Edge numerators, one wave per node (edges are row-sorted, 8 per node):
// row fragments loaded once; exact int8 dots in float; direct store (no atomic).
// ---------------------------------------------------------------------------
__global__ void edge_kernel(const char* __restrict__ Q1, const char* __restrict__ Q2,
                            const float* __restrict__ recip, const int* __restrict__ pos,
                            float* __restrict__ smp, float* __restrict__ ssc, int E)
{
    int row = blockIdx.x * (blockDim.x >> 6) + (threadIdx.x >> 6);
    int lane = threadIdx.x & 63;
    if (row >= NROWS) return;
    int2 a1 = ((const int2*)(Q1 + (size_t)row * HID))[lane];
    int2 a2 = ((const int2*)(Q2 + (size_t)row * HID))[lane];
    float s1 = 0.f, s2 = 0.f;
    float ir1 = recip[row], ir2 = recip[NROWS + row];
#pragma unroll
    for (int e = 0; e < 8; ++e) {
        int c = pos[E + row * 8 + e];
        int2 b2 = ((const int2*)(Q2 + (size_t)c * HID))[lane];
        int2 b1 = ((const int2*)(Q1 + (size_t)c * HID))[lane];
        float d1 = (float)(dot4i(a1.x, b2.x) + dot4i(a1.y, b2.y));
        float d2 = (float)(dot4i(b1.x, a2.x) + dot4i(b1.y, a2.y));
#pragma unroll
        for (int m = 1; m < 64; m <<= 1) {
            d1 += __shfl_xor(d1, m, 64);
            d2 += __shfl_xor(d2, m, 64);
        }
        if (lane == 0) {
            s1 += __expf(d1 * ir1 * recip[NROWS + c] * TAU_INV);   // S[row,c]
            s2 += __expf(d2 * recip[c] * ir2 * TAU_INV);           // S[c,row]
        }
    }
    if (lane == 0) { smp[row] = s1; ssc[row] = s2; }
}

// Single-block finalize: loss = mean over rows, written straight to out[0].
__global__ void finalize(const float* __restrict__ rowsum, const float* __restrict__ colsum,
                         const float* __restrict__ smp, const float* __restrict__ ssc,
                         float* __restrict__ out, int n)
{
    float contrib = 0.f;
    for (int i = threadIdx.x; i < n; i += blockDim.x) {
        float s1 = smp[i] / rowsum[i];
        float s2 = ssc[i] / colsum[i];
        contrib += -0.5f * (logf(s1) + logf(s2)) / (float)n;
    }
#pragma unroll
    for (int m = 1; m < 64; m <<= 1) contrib += __shfl_xor(contrib, m, 64);
    __shared__ float wsum[4];
    int w = threadIdx.x >> 6, lane = threadIdx.x & 63;
    if (lane == 0) wsum[w] = contrib;
    __syncthreads();
    if (threadIdx.x == 0) out[0] = wsum[0] + wsum[1] + wsum[2] + wsum[3];
}

extern "C" void kernel_launch(void* const* d_in, const int* in_sizes, int n_in,
                              void* d_out, int out_size, void* d_ws, size_t ws_size,
                              hipStream_t stream)
{
    const float* z_mp = (const float*)d_in[0];
    const float* z_sc = (const float*)d_in[1];
    const float* W1f  = (const float*)d_in[2];
    const float* b1   = (const float*)d_in[3];
    const float* W2f  = (const float*)d_in[4];
    const float* b2   = (const float*)d_in[5];
    const int*   pos  = (const int*)d_in[6];
    const int E = in_sizes[6] / 2;
    const int ZN = NROWS * HID;       // 4M elems
    const int WN = HID * HID;         // 256K elems

    // workspace layout (~34 MB):
    //   [0,16MB)   : Zb_mp, Zb_sc (bf16) -> dead after proj1 -> reused as P1,P2
    //   [16,32MB)  : H1,H2 (bf16) -> dead after proj2 -> reused as Q (int8, 8MB)
    //   [32MB,..)  : Wb1, Wb2, rowsum, colsum, recip(64KB), smp, ssc
    char* ws = (char*)d_ws;
    short* Zb1 = (short*)ws;
    short* Zb2 = Zb1 + ZN;
    short* P1  = Zb1;                 // alias: Zb dead after proj1
    short* P2  = Zb2;
    short* H1  = (short*)(ws + (size_t)16 * 1024 * 1024);
    short* H2  = H1 + ZN;
    char*  Q   = (char*)H1;           // alias: H dead after proj2; 2*NROWS rows
    char*  Q1  = Q;
    char*  Q2  = Q + (size_t)NROWS * HID;
    short* Wb1 = (short*)(ws + (size_t)32 * 1024 * 1024);
    short* Wb2 = Wb1 + WN;
    float* rowsum = (float*)(Wb2 + WN);
    float* colsum = rowsum + NROWS;
    float* recip  = colsum + NROWS;   // 2*NROWS floats
    float* smp    = recip + 2 * NROWS;
    float* ssc    = smp + NROWS;

    dim3 blk(256);
    // fp32 -> bf16 conversions (single launch)
    convert_all<<<dim3((2 * ZN + 2 * WN) / 1024), blk, 0, stream>>>(
        z_mp, z_sc, W1f, W2f, Zb1, Zb2, Wb1, Wb2);
    // zero rowsum+colsum (contiguous)
    hipMemsetAsync(rowsum, 0, 2 * NROWS * sizeof(float), stream);
    // H = elu(Z @ W1^T + b1) for both inputs (grid.z)
    gemm_proj<<<dim3(64, 4, 2), blk, 0, stream>>>(Zb1, Zb2, Wb1, b1, H1, H2, 1);
    // P = H @ W2^T + b2   (P overwrites Zb region — Zb dead now)
    gemm_proj<<<dim3(64, 4, 2), blk, 0, stream>>>(H1, H2, Wb2, b2, P1, P2, 0);
    // normalize + int8 quantize both P1,P2 (2*NROWS contiguous rows) -> Q, recip
    normalize_quant<<<dim3((2 * NROWS) / 4), blk, 0, stream>>>(P1, Q, recip, 2 * NROWS);
    // rowsum/colsum of exp-cosine similarity via i8 MFMA, XCD-swizzled grid
    gemm_sim<<<dim3(4096), blk, 0, stream>>>(Q1, Q2, recip, rowsum, colsum);
    // per-edge numerators, one wave per node, direct store
    edge_kernel<<<dim3(NROWS / 4), blk, 0, stream>>>(Q1, Q2, recip, pos, smp, ssc, E);
    // single-block reduce straight into d_out
    finalize<<<dim3(1), blk, 0, stream>>>(rowsum, colsum, smp, ssc, (float*)d_out, NROWS);
}

// Round 9
// 261.667 us; speedup vs baseline: 1.0019x; 1.0019x over previous
//
#include <hip/hip_runtime.h>

typedef __attribute__((ext_vector_type(8))) short s16x8;   // 8 bf16
typedef __attribute__((ext_vector_type(4))) float f32x4;
typedef __attribute__((ext_vector_type(4))) int   i32x4;

#define HID 512
#define NROWS 8192
#define TAU_INV 1.25f

__device__ __forceinline__ float bf2f(short s) {
    union { unsigned u; float f; } v;
    v.u = ((unsigned)(unsigned short)s) << 16;
    return v.f;
}
__device__ __forceinline__ short f2bf(float f) {
    unsigned u = __float_as_uint(f);
    u += 0x7fffu + ((u >> 16) & 1u);   // round-to-nearest-even
    return (short)(u >> 16);
}

__device__ __forceinline__ void gload_lds16(const void* g, void* l) {
    __builtin_amdgcn_global_load_lds(
        (const __attribute__((address_space(1))) unsigned int*)g,
        (__attribute__((address_space(3))) unsigned int*)l, 16, 0, 0);
}

__device__ __forceinline__ int dot4i(int a, int b) {
    int s = 0;
#pragma unroll
    for (int i = 0; i < 4; ++i)
        s += (int)(signed char)(a >> (8 * i)) * (int)(signed char)(b >> (8 * i));
    return s;
}

// ---------------------------------------------------------------------------
// Fused fp32->bf16 convert for z_mp, z_sc, W1, W2 + zeroing of rowsum/colsum
// (tail blocks), all in one launch.
// ---------------------------------------------------------------------------
__global__ void convert_all(const float* __restrict__ z1, const float* __restrict__ z2,
                            const float* __restrict__ w1, const float* __restrict__ w2,
                            short* __restrict__ Zb1, short* __restrict__ Zb2,
                            short* __restrict__ Wb1, short* __restrict__ Wb2,
                            float* __restrict__ zsum)
{
    const int ZN = NROWS * HID, WN = HID * HID;
    const int NCONV = (2 * ZN + 2 * WN) / 1024;   // conversion blocks
    if ((int)blockIdx.x >= NCONV) {               // tail: zero rowsum+colsum
        int zi = ((int)blockIdx.x - NCONV) * 1024 + threadIdx.x * 4;
        if (zi < 2 * NROWS)
            *(float4*)(zsum + zi) = make_float4(0.f, 0.f, 0.f, 0.f);
        return;
    }
    long i = (long)(blockIdx.x * blockDim.x + threadIdx.x) * 4;
    const float* src;
    short* dst;
    long off;
    if (i < ZN)                { src = z1; dst = Zb1; off = i; }
    else if (i < 2L * ZN)      { src = z2; dst = Zb2; off = i - ZN; }
    else if (i < 2L * ZN + WN) { src = w1; dst = Wb1; off = i - 2L * ZN; }
    else                       { src = w2; dst = Wb2; off = i - 2L * ZN - WN; }
    float4 v = *(const float4*)(src + off);
    short4 o;
    o.x = f2bf(v.x); o.y = f2bf(v.y); o.z = f2bf(v.z); o.w = f2bf(v.w);
    *(short4*)(dst + off) = o;
}

// ---------------------------------------------------------------------------
// bf16 NT GEMM — R2 structure verbatim (verified fastest of 5 variants):
// 128x128 tile, BK=32, row-major LDS (32-short rows), 4 waves of 64x64.
// ---------------------------------------------------------------------------
__global__ __launch_bounds__(256, 2)
void gemm_proj(const short* __restrict__ A0, const short* __restrict__ A1,
               const short* __restrict__ B, const float* __restrict__ bias,
               short* __restrict__ C0, short* __restrict__ C1, int do_elu)
{
    __shared__ short ldsA[128 * 32];
    __shared__ short ldsB[128 * 32];
    const short* A = blockIdx.z ? A1 : A0;
    short* C = blockIdx.z ? C1 : C0;
    const int tid = threadIdx.x;
    const int w = tid >> 6, lane = tid & 63;
    const int wm = w >> 1, wn = w & 1;
    const int quad = lane >> 4, r16 = lane & 15;
    const int bM = blockIdx.x * 128, bN = blockIdx.y * 128;
    const int lrow = lane >> 2, lcol = (lane & 3) * 8;

    f32x4 acc[4][4] = {};

    for (int k0 = 0; k0 < HID; k0 += 32) {
        __syncthreads();
#pragma unroll
        for (int i = 0; i < 2; ++i) {
            int r0 = (w * 2 + i) * 16;
            gload_lds16(A + (size_t)(bM + r0 + lrow) * HID + k0 + lcol, &ldsA[r0 * 32]);
            gload_lds16(B + (size_t)(bN + r0 + lrow) * HID + k0 + lcol, &ldsB[r0 * 32]);
        }
        __syncthreads();
        s16x8 af[4], bfr[4];
#pragma unroll
        for (int t = 0; t < 4; ++t) {
            af[t]  = *(const s16x8*)&ldsA[(wm * 64 + t * 16 + r16) * 32 + quad * 8];
            bfr[t] = *(const s16x8*)&ldsB[(wn * 64 + t * 16 + r16) * 32 + quad * 8];
        }
#pragma unroll
        for (int tm = 0; tm < 4; ++tm)
#pragma unroll
            for (int tn = 0; tn < 4; ++tn)
                acc[tm][tn] = __builtin_amdgcn_mfma_f32_16x16x32_bf16(
                    af[tm], bfr[tn], acc[tm][tn], 0, 0, 0);
    }

#pragma unroll
    for (int tn = 0; tn < 4; ++tn) {
        int gcol = bN + wn * 64 + tn * 16 + r16;
        float bv = bias[gcol];
#pragma unroll
        for (int tm = 0; tm < 4; ++tm) {
#pragma unroll
            for (int r = 0; r < 4; ++r) {
                int grow = bM + wm * 64 + tm * 16 + quad * 4 + r;  // C/D: row=(lane>>4)*4+reg
                float v = acc[tm][tn][r] + bv;
                if (do_elu) v = v > 0.f ? v : __expf(v) - 1.f;
                C[(size_t)grow * HID + gcol] = f2bf(v);
            }
        }
    }
}

// ---------------------------------------------------------------------------
// normalize + int8 row-quantize: q = round(n * 127/max|n_row|), one wave/row.
// recip[row] = max|n_row|/127, so dot_real = i32acc * recip[r] * recip[c].
// ---------------------------------------------------------------------------
__global__ void normalize_quant(const short* __restrict__ P, char* __restrict__ Q,
                                float* __restrict__ recip, int nrows)
{
    int gt = blockIdx.x * blockDim.x + threadIdx.x;
    int row = gt >> 6, lane = gt & 63;
    if (row >= nrows) return;
    const short* p = P + (size_t)row * HID + lane * 8;
    s16x8 v = *(const s16x8*)p;
    float f[8], ss = 0.f, am = 0.f;
#pragma unroll
    for (int i = 0; i < 8; ++i) {
        f[i] = bf2f(v[i]);
        ss += f[i] * f[i];
        am = fmaxf(am, fabsf(f[i]));
    }
#pragma unroll
    for (int m = 1; m < 64; m <<= 1) {
        ss += __shfl_xor(ss, m, 64);
        am = fmaxf(am, __shfl_xor(am, m, 64));
    }
    float inv = rsqrtf(ss);
    float maxn = am * inv;             // max |n_i| over the row
    float s = 127.f / maxn;
    int lo = 0, hi = 0;
#pragma unroll
    for (int i = 0; i < 4; ++i) {
        int q0 = (int)lrintf(f[i] * inv * s);
        int q1 = (int)lrintf(f[i + 4] * inv * s);
        lo |= (q0 & 255) << (8 * i);
        hi |= (q1 & 255) << (8 * i);
    }
    ((int2*)(Q + (size_t)row * HID))[lane] = make_int2(lo, hi);
    if (lane == 0) recip[row] = maxn * (1.f / 127.f);
}

// ---------------------------------------------------------------------------
// int8 similarity, 256x128 tile (2048 blocks): 32 MFMA per wave per barrier
// (2x R7) to amortize the measured ~15k-cyc fixed per-block cost. BK=64,
// LDS 24 KB, 4 waves each computing 128x64 (8x4 of mfma_i32_16x16x64_i8).
// ---------------------------------------------------------------------------
__global__ __launch_bounds__(256, 2)
void gemm_sim(const char* __restrict__ Q1, const char* __restrict__ Q2,
              const float* __restrict__ recip,
              float* __restrict__ rowsum, float* __restrict__ colsum)
{
    __shared__ char ldsA[256 * 64];   // 16 KB
    __shared__ char ldsB[128 * 64];   //  8 KB
    const int tid = threadIdx.x;
    const int w = tid >> 6, lane = tid & 63;
    const int wm = w >> 1, wn = w & 1;
    const int quad = lane >> 4, r16 = lane & 15;
    const int bM = blockIdx.x * 256, bN = blockIdx.y * 128;
    const int lrow = lane >> 2, lcol = (lane & 3) * 16;   // bytes within 64B row

    i32x4 acc[8][4] = {};

    for (int k0 = 0; k0 < HID; k0 += 64) {
        __syncthreads();
        // A: wave w stages rows [w*64, w*64+64): 4 x 1KB loads
#pragma unroll
        for (int i = 0; i < 4; ++i) {
            int r0 = w * 64 + i * 16;
            gload_lds16(Q1 + (size_t)(bM + r0 + lrow) * HID + k0 + lcol, &ldsA[r0 * 64]);
        }
        // B: wave w stages rows [w*32, w*32+32): 2 x 1KB loads
#pragma unroll
        for (int i = 0; i < 2; ++i) {
            int r0 = w * 32 + i * 16;
            gload_lds16(Q2 + (size_t)(bN + r0 + lrow) * HID + k0 + lcol, &ldsB[r0 * 64]);
        }
        __syncthreads();
        i32x4 af[8], bfr[4];
#pragma unroll
        for (int t = 0; t < 8; ++t)
            af[t] = *(const i32x4*)&ldsA[(wm * 128 + t * 16 + r16) * 64 + quad * 16];
#pragma unroll
        for (int t = 0; t < 4; ++t)
            bfr[t] = *(const i32x4*)&ldsB[(wn * 64 + t * 16 + r16) * 64 + quad * 16];
#pragma unroll
        for (int tm = 0; tm < 8; ++tm)
#pragma unroll
            for (int tn = 0; tn < 4; ++tn)
                acc[tm][tn] = __builtin_amdgcn_mfma_i32_16x16x64_i8(
                    af[tm], bfr[tn], acc[tm][tn], 0, 0, 0);
    }

    // epilogue: scale, exp, reduce. cb folds in TAU_INV.
    float cb[4], cs[4] = {0.f, 0.f, 0.f, 0.f};
#pragma unroll
    for (int tn = 0; tn < 4; ++tn)
        cb[tn] = recip[NROWS + bN + wn * 64 + tn * 16 + r16] * TAU_INV;

#pragma unroll
    for (int tm = 0; tm < 8; ++tm) {
#pragma unroll
        for (int r = 0; r < 4; ++r) {
            int grow = bM + wm * 128 + tm * 16 + quad * 4 + r;  // C/D: row=quad*4+reg
            float ra = recip[grow];
            float rs = 0.f;
#pragma unroll
            for (int tn = 0; tn < 4; ++tn) {
                float e = __expf((float)acc[tm][tn][r] * ra * cb[tn]);
                rs += e;
                cs[tn] += e;
            }
#pragma unroll
            for (int m = 1; m < 16; m <<= 1) rs += __shfl_xor(rs, m, 64);
            if (r16 == 0) atomicAdd(&rowsum[grow], rs);
        }
    }
#pragma unroll
    for (int tn = 0; tn < 4; ++tn) {
        float c = cs[tn];
        c += __shfl_xor(c, 16, 64);
        c += __shfl_xor(c, 32, 64);
        if (quad == 0)
            atomicAdd(&colsum[bN + wn * 64 + tn * 16 + r16], c);
    }
}

// ---------------------------------------------------------------------------
// Edge numerators, one wave per node (edges are row-sorted, 8 per node):
// row fragments loaded once; exact int8 dots in float; direct store (no atomic).
// ---------------------------------------------------------------------------
__global__ void edge_kernel(const char* __restrict__ Q1, const char* __restrict__ Q2,
                            const float* __restrict__ recip, const int* __restrict__ pos,
                            float* __restrict__ smp, float* __restrict__ ssc, int E)
{
    int row = blockIdx.x * (blockDim.x >> 6) + (threadIdx.x >> 6);
    int lane = threadIdx.x & 63;
    if (row >= NROWS) return;
    int2 a1 = ((const int2*)(Q1 + (size_t)row * HID))[lane];
    int2 a2 = ((const int2*)(Q2 + (size_t)row * HID))[lane];
    float s1 = 0.f, s2 = 0.f;
    float ir1 = recip[row], ir2 = recip[NROWS + row];
#pragma unroll
    for (int e = 0; e < 8; ++e) {
        int c = pos[E + row * 8 + e];
        int2 b2 = ((const int2*)(Q2 + (size_t)c * HID))[lane];
        int2 b1 = ((const int2*)(Q1 + (size_t)c * HID))[lane];
        float d1 = (float)(dot4i(a1.x, b2.x) + dot4i(a1.y, b2.y));
        float d2 = (float)(dot4i(b1.x, a2.x) + dot4i(b1.y, a2.y));
#pragma unroll
        for (int m = 1; m < 64; m <<= 1) {
            d1 += __shfl_xor(d1, m, 64);
            d2 += __shfl_xor(d2, m, 64);
        }
        if (lane == 0) {
            s1 += __expf(d1 * ir1 * recip[NROWS + c] * TAU_INV);   // S[row,c]
            s2 += __expf(d2 * recip[c] * ir2 * TAU_INV);           // S[c,row]
        }
    }
    if (lane == 0) { smp[row] = s1; ssc[row] = s2; }
}

// Single-block finalize: loss = mean over rows, written straight to out[0].
__global__ void finalize(const float* __restrict__ rowsum, const float* __restrict__ colsum,
                         const float* __restrict__ smp, const float* __restrict__ ssc,
                         float* __restrict__ out, int n)
{
    float contrib = 0.f;
    for (int i = threadIdx.x; i < n; i += blockDim.x) {
        float s1 = smp[i] / rowsum[i];
        float s2 = ssc[i] / colsum[i];
        contrib += -0.5f * (logf(s1) + logf(s2)) / (float)n;
    }
#pragma unroll
    for (int m = 1; m < 64; m <<= 1) contrib += __shfl_xor(contrib, m, 64);
    __shared__ float wsum[4];
    int w = threadIdx.x >> 6, lane = threadIdx.x & 63;
    if (lane == 0) wsum[w] = contrib;
    __syncthreads();
    if (threadIdx.x == 0) out[0] = wsum[0] + wsum[1] + wsum[2] + wsum[3];
}

extern "C" void kernel_launch(void* const* d_in, const int* in_sizes, int n_in,
                              void* d_out, int out_size, void* d_ws, size_t ws_size,
                              hipStream_t stream)
{
    const float* z_mp = (const float*)d_in[0];
    const float* z_sc = (const float*)d_in[1];
    const float* W1f  = (const float*)d_in[2];
    const float* b1   = (const float*)d_in[3];
    const float* W2f  = (const float*)d_in[4];
    const float* b2   = (const float*)d_in[5];
    const int*   pos  = (const int*)d_in[6];
    const int E = in_sizes[6] / 2;
    const int ZN = NROWS * HID;       // 4M elems
    const int WN = HID * HID;         // 256K elems

    // workspace layout (~34 MB):
    //   [0,16MB)   : Zb_mp, Zb_sc (bf16) -> dead after proj1 -> reused as P1,P2
    //   [16,32MB)  : H1,H2 (bf16) -> dead after proj2 -> reused as Q (int8, 8MB)
    //   [32MB,..)  : Wb1, Wb2, rowsum, colsum, recip(64KB), smp, ssc
    char* ws = (char*)d_ws;
    short* Zb1 = (short*)ws;
    short* Zb2 = Zb1 + ZN;
    short* P1  = Zb1;                 // alias: Zb dead after proj1
    short* P2  = Zb2;
    short* H1  = (short*)(ws + (size_t)16 * 1024 * 1024);
    short* H2  = H1 + ZN;
    char*  Q   = (char*)H1;           // alias: H dead after proj2; 2*NROWS rows
    char*  Q1  = Q;
    char*  Q2  = Q + (size_t)NROWS * HID;
    short* Wb1 = (short*)(ws + (size_t)32 * 1024 * 1024);
    short* Wb2 = Wb1 + WN;
    float* rowsum = (float*)(Wb2 + WN);
    float* colsum = rowsum + NROWS;
    float* recip  = colsum + NROWS;   // 2*NROWS floats
    float* smp    = recip + 2 * NROWS;
    float* ssc    = smp + NROWS;

    dim3 blk(256);
    // fp32 -> bf16 conversions + rowsum/colsum zeroing (single launch)
    convert_all<<<dim3((2 * ZN + 2 * WN) / 1024 + 16), blk, 0, stream>>>(
        z_mp, z_sc, W1f, W2f, Zb1, Zb2, Wb1, Wb2, rowsum);
    // H = elu(Z @ W1^T + b1) for both inputs (grid.z)
    gemm_proj<<<dim3(64, 4, 2), blk, 0, stream>>>(Zb1, Zb2, Wb1, b1, H1, H2, 1);
    // P = H @ W2^T + b2   (P overwrites Zb region — Zb dead now)
    gemm_proj<<<dim3(64, 4, 2), blk, 0, stream>>>(H1, H2, Wb2, b2, P1, P2, 0);
    // normalize + int8 quantize both P1,P2 (2*NROWS contiguous rows) -> Q, recip
    normalize_quant<<<dim3((2 * NROWS) / 4), blk, 0, stream>>>(P1, Q, recip, 2 * NROWS);
    // rowsum/colsum of exp-cosine similarity via i8 MFMA, 256x128 tiles
    gemm_sim<<<dim3(32, 64), blk, 0, stream>>>(Q1, Q2, recip, rowsum, colsum);
    // per-edge numerators, one wave per node, direct store
    edge_kernel<<<dim3(NROWS / 4), blk, 0, stream>>>(Q1, Q2, recip, pos, smp, ssc, E);
    // single-block reduce straight into d_out
    finalize<<<dim3(1), blk, 0, stream>>>(rowsum, colsum, smp, ssc, (float*)d_out, NROWS);
}

// Round 10
// 255.715 us; speedup vs baseline: 1.0252x; 1.0233x over previous
//
#include <hip/hip_runtime.h>

typedef __attribute__((ext_vector_type(8))) short s16x8;   // 8 bf16
typedef __attribute__((ext_vector_type(4))) float f32x4;
typedef __attribute__((ext_vector_type(4))) int   i32x4;

#define HID 512
#define NROWS 8192
#define TAU_INV 1.25f

__device__ __forceinline__ float bf2f(short s) {
    union { unsigned u; float f; } v;
    v.u = ((unsigned)(unsigned short)s) << 16;
    return v.f;
}
__device__ __forceinline__ short f2bf(float f) {
    unsigned u = __float_as_uint(f);
    u += 0x7fffu + ((u >> 16) & 1u);   // round-to-nearest-even
    return (short)(u >> 16);
}

__device__ __forceinline__ void gload_lds16(const void* g, void* l) {
    __builtin_amdgcn_global_load_lds(
        (const __attribute__((address_space(1))) unsigned int*)g,
        (__attribute__((address_space(3))) unsigned int*)l, 16, 0, 0);
}

__device__ __forceinline__ int dot4i(int a, int b) {
    int s = 0;
#pragma unroll
    for (int i = 0; i < 4; ++i)
        s += (int)(signed char)(a >> (8 * i)) * (int)(signed char)(b >> (8 * i));
    return s;
}

// ---------------------------------------------------------------------------
// Fused fp32->bf16 convert for z_mp, z_sc, W1, W2 + zeroing of rowsum/colsum
// (tail blocks), all in one launch.
// ---------------------------------------------------------------------------
__global__ void convert_all(const float* __restrict__ z1, const float* __restrict__ z2,
                            const float* __restrict__ w1, const float* __restrict__ w2,
                            short* __restrict__ Zb1, short* __restrict__ Zb2,
                            short* __restrict__ Wb1, short* __restrict__ Wb2,
                            float* __restrict__ zsum)
{
    const int ZN = NROWS * HID, WN = HID * HID;
    const int NCONV = (2 * ZN + 2 * WN) / 1024;   // conversion blocks
    if ((int)blockIdx.x >= NCONV) {               // tail: zero rowsum+colsum
        int zi = ((int)blockIdx.x - NCONV) * 1024 + threadIdx.x * 4;
        if (zi < 2 * NROWS)
            *(float4*)(zsum + zi) = make_float4(0.f, 0.f, 0.f, 0.f);
        return;
    }
    long i = (long)(blockIdx.x * blockDim.x + threadIdx.x) * 4;
    const float* src;
    short* dst;
    long off;
    if (i < ZN)                { src = z1; dst = Zb1; off = i; }
    else if (i < 2L * ZN)      { src = z2; dst = Zb2; off = i - ZN; }
    else if (i < 2L * ZN + WN) { src = w1; dst = Wb1; off = i - 2L * ZN; }
    else                       { src = w2; dst = Wb2; off = i - 2L * ZN - WN; }
    float4 v = *(const float4*)(src + off);
    short4 o;
    o.x = f2bf(v.x); o.y = f2bf(v.y); o.z = f2bf(v.z); o.w = f2bf(v.w);
    *(short4*)(dst + off) = o;
}

// ---------------------------------------------------------------------------
// bf16 NT GEMM — R2 structure verbatim (verified fastest):
// 128x128 tile, BK=32, row-major LDS (32-short rows), 4 waves of 64x64.
// ---------------------------------------------------------------------------
__global__ __launch_bounds__(256, 2)
void gemm_proj(const short* __restrict__ A0, const short* __restrict__ A1,
               const short* __restrict__ B, const float* __restrict__ bias,
               short* __restrict__ C0, short* __restrict__ C1, int do_elu)
{
    __shared__ short ldsA[128 * 32];
    __shared__ short ldsB[128 * 32];
    const short* A = blockIdx.z ? A1 : A0;
    short* C = blockIdx.z ? C1 : C0;
    const int tid = threadIdx.x;
    const int w = tid >> 6, lane = tid & 63;
    const int wm = w >> 1, wn = w & 1;
    const int quad = lane >> 4, r16 = lane & 15;
    const int bM = blockIdx.x * 128, bN = blockIdx.y * 128;
    const int lrow = lane >> 2, lcol = (lane & 3) * 8;

    f32x4 acc[4][4] = {};

    for (int k0 = 0; k0 < HID; k0 += 32) {
        __syncthreads();
#pragma unroll
        for (int i = 0; i < 2; ++i) {
            int r0 = (w * 2 + i) * 16;
            gload_lds16(A + (size_t)(bM + r0 + lrow) * HID + k0 + lcol, &ldsA[r0 * 32]);
            gload_lds16(B + (size_t)(bN + r0 + lrow) * HID + k0 + lcol, &ldsB[r0 * 32]);
        }
        __syncthreads();
        s16x8 af[4], bfr[4];
#pragma unroll
        for (int t = 0; t < 4; ++t) {
            af[t]  = *(const s16x8*)&ldsA[(wm * 64 + t * 16 + r16) * 32 + quad * 8];
            bfr[t] = *(const s16x8*)&ldsB[(wn * 64 + t * 16 + r16) * 32 + quad * 8];
        }
#pragma unroll
        for (int tm = 0; tm < 4; ++tm)
#pragma unroll
            for (int tn = 0; tn < 4; ++tn)
                acc[tm][tn] = __builtin_amdgcn_mfma_f32_16x16x32_bf16(
                    af[tm], bfr[tn], acc[tm][tn], 0, 0, 0);
    }

#pragma unroll
    for (int tn = 0; tn < 4; ++tn) {
        int gcol = bN + wn * 64 + tn * 16 + r16;
        float bv = bias[gcol];
#pragma unroll
        for (int tm = 0; tm < 4; ++tm) {
#pragma unroll
            for (int r = 0; r < 4; ++r) {
                int grow = bM + wm * 64 + tm * 16 + quad * 4 + r;  // C/D: row=(lane>>4)*4+reg
                float v = acc[tm][tn][r] + bv;
                if (do_elu) v = v > 0.f ? v : __expf(v) - 1.f;
                C[(size_t)grow * HID + gcol] = f2bf(v);
            }
        }
    }
}

// ---------------------------------------------------------------------------
// normalize + int8 row-quantize: q = round(n * 127/max|n_row|), one wave/row.
// recip[row] = max|n_row|/127, so dot_real = i32acc * recip[r] * recip[c].
// ---------------------------------------------------------------------------
__global__ void normalize_quant(const short* __restrict__ P, char* __restrict__ Q,
                                float* __restrict__ recip, int nrows)
{
    int gt = blockIdx.x * blockDim.x + threadIdx.x;
    int row = gt >> 6, lane = gt & 63;
    if (row >= nrows) return;
    const short* p = P + (size_t)row * HID + lane * 8;
    s16x8 v = *(const s16x8*)p;
    float f[8], ss = 0.f, am = 0.f;
#pragma unroll
    for (int i = 0; i < 8; ++i) {
        f[i] = bf2f(v[i]);
        ss += f[i] * f[i];
        am = fmaxf(am, fabsf(f[i]));
    }
#pragma unroll
    for (int m = 1; m < 64; m <<= 1) {
        ss += __shfl_xor(ss, m, 64);
        am = fmaxf(am, __shfl_xor(am, m, 64));
    }
    float inv = rsqrtf(ss);
    float maxn = am * inv;             // max |n_i| over the row
    float s = 127.f / maxn;
    int lo = 0, hi = 0;
#pragma unroll
    for (int i = 0; i < 4; ++i) {
        int q0 = (int)lrintf(f[i] * inv * s);
        int q1 = (int)lrintf(f[i + 4] * inv * s);
        lo |= (q0 & 255) << (8 * i);
        hi |= (q1 & 255) << (8 * i);
    }
    ((int2*)(Q + (size_t)row * HID))[lane] = make_int2(lo, hi);
    if (lane == 0) recip[row] = maxn * (1.f / 127.f);
}

// ---------------------------------------------------------------------------
// int8 similarity, BARRIER-FREE K-loop. Block = 128 rows x 1024 cols.
// A panel (128x512 i8 = 64KB) staged to LDS ONCE (one barrier), stored as
// 8 chunks of [128 rows x 64B] with XOR bank swizzle:
//   LDS slot(row, s) holds global k-chunk (s ^ ((row>>1)&3)) of that row.
// The swizzle is applied to the STAGING SOURCE address (dest must stay
// base + lane*16 for global_load_lds). ds_read of a fragment then maps
// 16 lanes -> 8 bank-groups x 2-way = conflict-free (m136: 2-way free).
// B fragments stream global->register, double-buffered: NO barriers in the
// 64-iteration (8 col-tiles x 8 k-chunks) MFMA loop -> fine-grained vmcnt.
// ---------------------------------------------------------------------------
__global__ __launch_bounds__(256, 2)
void gemm_sim(const char* __restrict__ Q1, const char* __restrict__ Q2,
              const float* __restrict__ recip,
              float* __restrict__ rowsum, float* __restrict__ colsum)
{
    __shared__ char ldsA[8 * 8192];   // 64 KB
    const int tid = threadIdx.x;
    const int w = tid >> 6, lane = tid & 63;
    const int wm = w >> 1, wn = w & 1;
    const int quad = lane >> 4, r16 = lane & 15;
    const int bM = blockIdx.x * 128;                  // 64 row-blocks
    const int cg = blockIdx.y;                        // 8 col-groups (1024 cols each)
    const int lrow = lane >> 2;                       // 0..15
    const int lq   = (lane & 3) ^ ((lane >> 3) & 3);  // swizzled source k-slot

    // ---- stage entire A panel (wave w: chunks 2w, 2w+1), one barrier ----
#pragma unroll
    for (int cc = 0; cc < 2; ++cc) {
        int c = w * 2 + cc;
#pragma unroll
        for (int i = 0; i < 8; ++i) {
            int r0 = i * 16;
            gload_lds16(Q1 + (size_t)(bM + r0 + lrow) * HID + c * 64 + lq * 16,
                        &ldsA[c * 8192 + r0 * 64]);
        }
    }
    __syncthreads();

    // row-scale factors, hoisted (row = bM + wm*64 + tm*16 + quad*4 + r)
    float ra[4][4];
#pragma unroll
    for (int tm = 0; tm < 4; ++tm)
#pragma unroll
        for (int r = 0; r < 4; ++r)
            ra[tm][r] = recip[bM + wm * 64 + tm * 16 + quad * 4 + r];

    float rs_acc[4][4] = {};   // per-lane rowsum partials across col-tiles

    // B fragment base: col = cg*1024 + j*128 + wn*64 + t*16 + r16, k-chunk quad
    const char* Bb = Q2 + (size_t)(cg * 1024 + wn * 64 + r16) * HID + quad * 16;
    const int aswz = (quad ^ ((r16 >> 1) & 3)) * 16;   // swizzled ds_read slot

    i32x4 bbuf[2][4];
#pragma unroll
    for (int t = 0; t < 4; ++t)
        bbuf[0][t] = *(const i32x4*)(Bb + (size_t)t * 16 * HID);

    for (int j = 0; j < 8; ++j) {
        i32x4 acc[4][4] = {};
        const char* Bj = Bb + (size_t)j * 128 * HID;
#pragma unroll
        for (int k = 0; k < 8; ++k) {
            const int cur = k & 1, nxt = cur ^ 1;
            if (j < 7 || k < 7) {
                const char* Bn = (k < 7) ? (Bj + (k + 1) * 64)
                                         : (Bb + (size_t)(j + 1) * 128 * HID);
#pragma unroll
                for (int t = 0; t < 4; ++t)
                    bbuf[nxt][t] = *(const i32x4*)(Bn + (size_t)t * 16 * HID);
            }
            i32x4 af[4];
#pragma unroll
            for (int t = 0; t < 4; ++t)
                af[t] = *(const i32x4*)&ldsA[k * 8192
                        + (wm * 64 + t * 16 + r16) * 64 + aswz];
#pragma unroll
            for (int tm = 0; tm < 4; ++tm)
#pragma unroll
                for (int tn = 0; tn < 4; ++tn)
                    acc[tm][tn] = __builtin_amdgcn_mfma_i32_16x16x64_i8(
                        af[tm], bbuf[cur][tn], acc[tm][tn], 0, 0, 0);
        }
        // ---- epilogue for col-tile j: exp, colsum atomics, rowsum to regs ----
        const int colbase = cg * 1024 + j * 128 + wn * 64;
        float cb[4], cs[4] = {0.f, 0.f, 0.f, 0.f};
#pragma unroll
        for (int tn = 0; tn < 4; ++tn)
            cb[tn] = recip[NROWS + colbase + tn * 16 + r16] * TAU_INV;
#pragma unroll
        for (int tm = 0; tm < 4; ++tm) {
#pragma unroll
            for (int r = 0; r < 4; ++r) {
                float rav = ra[tm][r];
#pragma unroll
                for (int tn = 0; tn < 4; ++tn) {
                    float e = __expf((float)acc[tm][tn][r] * rav * cb[tn]);
                    rs_acc[tm][r] += e;
                    cs[tn] += e;
                }
            }
        }
#pragma unroll
        for (int tn = 0; tn < 4; ++tn) {
            float c = cs[tn];
            c += __shfl_xor(c, 16, 64);
            c += __shfl_xor(c, 32, 64);
            if (quad == 0)
                atomicAdd(&colsum[colbase + tn * 16 + r16], c);
        }
    }

    // ---- final rowsum: reduce over the 16 r16-lanes, 1 atomic/row/block ----
#pragma unroll
    for (int tm = 0; tm < 4; ++tm) {
#pragma unroll
        for (int r = 0; r < 4; ++r) {
            float rs = rs_acc[tm][r];
#pragma unroll
            for (int m = 1; m < 16; m <<= 1) rs += __shfl_xor(rs, m, 64);
            if (r16 == 0)
                atomicAdd(&rowsum[bM + wm * 64 + tm * 16 + quad * 4 + r], rs);
        }
    }
}

// ---------------------------------------------------------------------------
// Edge numerators, one wave per node (edges are row-sorted, 8 per node):
// row fragments loaded once; exact int8 dots in float; direct store (no atomic).
// ---------------------------------------------------------------------------
__global__ void edge_kernel(const char* __restrict__ Q1, const char* __restrict__ Q2,
                            const float* __restrict__ recip, const int* __restrict__ pos,
                            float* __restrict__ smp, float* __restrict__ ssc, int E)
{
    int row = blockIdx.x * (blockDim.x >> 6) + (threadIdx.x >> 6);
    int lane = threadIdx.x & 63;
    if (row >= NROWS) return;
    int2 a1 = ((const int2*)(Q1 + (size_t)row * HID))[lane];
    int2 a2 = ((const int2*)(Q2 + (size_t)row * HID))[lane];
    float s1 = 0.f, s2 = 0.f;
    float ir1 = recip[row], ir2 = recip[NROWS + row];
#pragma unroll
    for (int e = 0; e < 8; ++e) {
        int c = pos[E + row * 8 + e];
        int2 b2 = ((const int2*)(Q2 + (size_t)c * HID))[lane];
        int2 b1 = ((const int2*)(Q1 + (size_t)c * HID))[lane];
        float d1 = (float)(dot4i(a1.x, b2.x) + dot4i(a1.y, b2.y));
        float d2 = (float)(dot4i(b1.x, a2.x) + dot4i(b1.y, a2.y));
#pragma unroll
        for (int m = 1; m < 64; m <<= 1) {
            d1 += __shfl_xor(d1, m, 64);
            d2 += __shfl_xor(d2, m, 64);
        }
        if (lane == 0) {
            s1 += __expf(d1 * ir1 * recip[NROWS + c] * TAU_INV);   // S[row,c]
            s2 += __expf(d2 * recip[c] * ir2 * TAU_INV);           // S[c,row]
        }
    }
    if (lane == 0) { smp[row] = s1; ssc[row] = s2; }
}

// Single-block finalize: loss = mean over rows, written straight to out[0].
__global__ void finalize(const float* __restrict__ rowsum, const float* __restrict__ colsum,
                         const float* __restrict__ smp, const float* __restrict__ ssc,
                         float* __restrict__ out, int n)
{
    float contrib = 0.f;
    for (int i = threadIdx.x; i < n; i += blockDim.x) {
        float s1 = smp[i] / rowsum[i];
        float s2 = ssc[i] / colsum[i];
        contrib += -0.5f * (logf(s1) + logf(s2)) / (float)n;
    }
#pragma unroll
    for (int m = 1; m < 64; m <<= 1) contrib += __shfl_xor(contrib, m, 64);
    __shared__ float wsum[4];
    int w = threadIdx.x >> 6, lane = threadIdx.x & 63;
    if (lane == 0) wsum[w] = contrib;
    __syncthreads();
    if (threadIdx.x == 0) out[0] = wsum[0] + wsum[1] + wsum[2] + wsum[3];
}

extern "C" void kernel_launch(void* const* d_in, const int* in_sizes, int n_in,
                              void* d_out, int out_size, void* d_ws, size_t ws_size,
                              hipStream_t stream)
{
    const float* z_mp = (const float*)d_in[0];
    const float* z_sc = (const float*)d_in[1];
    const float* W1f  = (const float*)d_in[2];
    const float* b1   = (const float*)d_in[3];
    const float* W2f  = (const float*)d_in[4];
    const float* b2   = (const float*)d_in[5];
    const int*   pos  = (const int*)d_in[6];
    const int E = in_sizes[6] / 2;
    const int ZN = NROWS * HID;       // 4M elems
    const int WN = HID * HID;         // 256K elems

    // workspace layout (~34 MB):
    //   [0,16MB)   : Zb_mp, Zb_sc (bf16) -> dead after proj1 -> reused as P1,P2
    //   [16,32MB)  : H1,H2 (bf16) -> dead after proj2 -> reused as Q (int8, 8MB)
    //   [32MB,..)  : Wb1, Wb2, rowsum, colsum, recip(64KB), smp, ssc
    char* ws = (char*)d_ws;
    short* Zb1 = (short*)ws;
    short* Zb2 = Zb1 + ZN;
    short* P1  = Zb1;                 // alias: Zb dead after proj1
    short* P2  = Zb2;
    short* H1  = (short*)(ws + (size_t)16 * 1024 * 1024);
    short* H2  = H1 + ZN;
    char*  Q   = (char*)H1;           // alias: H dead after proj2; 2*NROWS rows
    char*  Q1  = Q;
    char*  Q2  = Q + (size_t)NROWS * HID;
    short* Wb1 = (short*)(ws + (size_t)32 * 1024 * 1024);
    short* Wb2 = Wb1 + WN;
    float* rowsum = (float*)(Wb2 + WN);
    float* colsum = rowsum + NROWS;
    float* recip  = colsum + NROWS;   // 2*NROWS floats
    float* smp    = recip + 2 * NROWS;
    float* ssc    = smp + NROWS;

    dim3 blk(256);
    // fp32 -> bf16 conversions + rowsum/colsum zeroing (single launch)
    convert_all<<<dim3((2 * ZN + 2 * WN) / 1024 + 16), blk, 0, stream>>>(
        z_mp, z_sc, W1f, W2f, Zb1, Zb2, Wb1, Wb2, rowsum);
    // H = elu(Z @ W1^T + b1) for both inputs (grid.z)
    gemm_proj<<<dim3(64, 4, 2), blk, 0, stream>>>(Zb1, Zb2, Wb1, b1, H1, H2, 1);
    // P = H @ W2^T + b2   (P overwrites Zb region — Zb dead now)
    gemm_proj<<<dim3(64, 4, 2), blk, 0, stream>>>(H1, H2, Wb2, b2, P1, P2, 0);
    // normalize + int8 quantize both P1,P2 (2*NROWS contiguous rows) -> Q, recip
    normalize_quant<<<dim3((2 * NROWS) / 4), blk, 0, stream>>>(P1, Q, recip, 2 * NROWS);
    // rowsum/colsum via barrier-free i8 MFMA K-stream (A panel LDS-resident)
    gemm_sim<<<dim3(64, 8), blk, 0, stream>>>(Q1, Q2, recip, rowsum, colsum);
    // per-edge numerators, one wave per node, direct store
    edge_kernel<<<dim3(NROWS / 4), blk, 0, stream>>>(Q1, Q2, recip, pos, smp, ssc, E);
    // single-block reduce straight into d_out
    finalize<<<dim3(1), blk, 0, stream>>>(rowsum, colsum, smp, ssc, (float*)d_out, NROWS);
}

// Round 11
// 243.729 us; speedup vs baseline: 1.0756x; 1.0492x over previous
//
#include <hip/hip_runtime.h>

typedef __attribute__((ext_vector_type(8))) short s16x8;   // 8 bf16
typedef __attribute__((ext_vector_type(4))) float f32x4;
typedef __attribute__((ext_vector_type(4))) int   i32x4;

#define HID 512
#define NROWS 8192
#define TAU_INV 1.25f
#define LOG2E 1.4426950408889634f

__device__ __forceinline__ float bf2f(short s) {
    union { unsigned u; float f; } v;
    v.u = ((unsigned)(unsigned short)s) << 16;
    return v.f;
}
__device__ __forceinline__ short f2bf(float f) {
    unsigned u = __float_as_uint(f);
    u += 0x7fffu + ((u >> 16) & 1u);   // round-to-nearest-even
    return (short)(u >> 16);
}

__device__ __forceinline__ void gload_lds16(const void* g, void* l) {
    __builtin_amdgcn_global_load_lds(
        (const __attribute__((address_space(1))) unsigned int*)g,
        (__attribute__((address_space(3))) unsigned int*)l, 16, 0, 0);
}

__device__ __forceinline__ int dot4i(int a, int b) {
    int s = 0;
#pragma unroll
    for (int i = 0; i < 4; ++i)
        s += (int)(signed char)(a >> (8 * i)) * (int)(signed char)(b >> (8 * i));
    return s;
}

// ---------------------------------------------------------------------------
// Fused fp32->bf16 convert for z_mp, z_sc, W1, W2 + zeroing of rowsum/colsum
// (tail blocks), all in one launch.
// ---------------------------------------------------------------------------
__global__ void convert_all(const float* __restrict__ z1, const float* __restrict__ z2,
                            const float* __restrict__ w1, const float* __restrict__ w2,
                            short* __restrict__ Zb1, short* __restrict__ Zb2,
                            short* __restrict__ Wb1, short* __restrict__ Wb2,
                            float* __restrict__ zsum)
{
    const int ZN = NROWS * HID, WN = HID * HID;
    const int NCONV = (2 * ZN + 2 * WN) / 1024;   // conversion blocks
    if ((int)blockIdx.x >= NCONV) {               // tail: zero rowsum+colsum
        int zi = ((int)blockIdx.x - NCONV) * 1024 + threadIdx.x * 4;
        if (zi < 2 * NROWS)
            *(float4*)(zsum + zi) = make_float4(0.f, 0.f, 0.f, 0.f);
        return;
    }
    long i = (long)(blockIdx.x * blockDim.x + threadIdx.x) * 4;
    const float* src;
    short* dst;
    long off;
    if (i < ZN)                { src = z1; dst = Zb1; off = i; }
    else if (i < 2L * ZN)      { src = z2; dst = Zb2; off = i - ZN; }
    else if (i < 2L * ZN + WN) { src = w1; dst = Wb1; off = i - 2L * ZN; }
    else                       { src = w2; dst = Wb2; off = i - 2L * ZN - WN; }
    float4 v = *(const float4*)(src + off);
    short4 o;
    o.x = f2bf(v.x); o.y = f2bf(v.y); o.z = f2bf(v.z); o.w = f2bf(v.w);
    *(short4*)(dst + off) = o;
}

// ---------------------------------------------------------------------------
// bf16 NT GEMM — R2 structure (verified fastest); launch_bounds 3 for an
// extra co-resident block (regs ~130 < 170 cap).
// ---------------------------------------------------------------------------
__global__ __launch_bounds__(256, 3)
void gemm_proj(const short* __restrict__ A0, const short* __restrict__ A1,
               const short* __restrict__ B, const float* __restrict__ bias,
               short* __restrict__ C0, short* __restrict__ C1, int do_elu)
{
    __shared__ short ldsA[128 * 32];
    __shared__ short ldsB[128 * 32];
    const short* A = blockIdx.z ? A1 : A0;
    short* C = blockIdx.z ? C1 : C0;
    const int tid = threadIdx.x;
    const int w = tid >> 6, lane = tid & 63;
    const int wm = w >> 1, wn = w & 1;
    const int quad = lane >> 4, r16 = lane & 15;
    const int bM = blockIdx.x * 128, bN = blockIdx.y * 128;
    const int lrow = lane >> 2, lcol = (lane & 3) * 8;

    f32x4 acc[4][4] = {};

    for (int k0 = 0; k0 < HID; k0 += 32) {
        __syncthreads();
#pragma unroll
        for (int i = 0; i < 2; ++i) {
            int r0 = (w * 2 + i) * 16;
            gload_lds16(A + (size_t)(bM + r0 + lrow) * HID + k0 + lcol, &ldsA[r0 * 32]);
            gload_lds16(B + (size_t)(bN + r0 + lrow) * HID + k0 + lcol, &ldsB[r0 * 32]);
        }
        __syncthreads();
        s16x8 af[4], bfr[4];
#pragma unroll
        for (int t = 0; t < 4; ++t) {
            af[t]  = *(const s16x8*)&ldsA[(wm * 64 + t * 16 + r16) * 32 + quad * 8];
            bfr[t] = *(const s16x8*)&ldsB[(wn * 64 + t * 16 + r16) * 32 + quad * 8];
        }
#pragma unroll
        for (int tm = 0; tm < 4; ++tm)
#pragma unroll
            for (int tn = 0; tn < 4; ++tn)
                acc[tm][tn] = __builtin_amdgcn_mfma_f32_16x16x32_bf16(
                    af[tm], bfr[tn], acc[tm][tn], 0, 0, 0);
    }

#pragma unroll
    for (int tn = 0; tn < 4; ++tn) {
        int gcol = bN + wn * 64 + tn * 16 + r16;
        float bv = bias[gcol];
#pragma unroll
        for (int tm = 0; tm < 4; ++tm) {
#pragma unroll
            for (int r = 0; r < 4; ++r) {
                int grow = bM + wm * 64 + tm * 16 + quad * 4 + r;  // C/D: row=(lane>>4)*4+reg
                float v = acc[tm][tn][r] + bv;
                if (do_elu) v = v > 0.f ? v : __expf(v) - 1.f;
                C[(size_t)grow * HID + gcol] = f2bf(v);
            }
        }
    }
}

// ---------------------------------------------------------------------------
// normalize + int8 row-quantize: q = round(n * 127/max|n_row|), one wave/row.
// recip[row] = max|n_row|/127, so dot_real = i32acc * recip[r] * recip[c].
// ---------------------------------------------------------------------------
__global__ void normalize_quant(const short* __restrict__ P, char* __restrict__ Q,
                                float* __restrict__ recip, int nrows)
{
    int gt = blockIdx.x * blockDim.x + threadIdx.x;
    int row = gt >> 6, lane = gt & 63;
    if (row >= nrows) return;
    const short* p = P + (size_t)row * HID + lane * 8;
    s16x8 v = *(const s16x8*)p;
    float f[8], ss = 0.f, am = 0.f;
#pragma unroll
    for (int i = 0; i < 8; ++i) {
        f[i] = bf2f(v[i]);
        ss += f[i] * f[i];
        am = fmaxf(am, fabsf(f[i]));
    }
#pragma unroll
    for (int m = 1; m < 64; m <<= 1) {
        ss += __shfl_xor(ss, m, 64);
        am = fmaxf(am, __shfl_xor(am, m, 64));
    }
    float inv = rsqrtf(ss);
    float maxn = am * inv;             // max |n_i| over the row
    float s = 127.f / maxn;
    int lo = 0, hi = 0;
#pragma unroll
    for (int i = 0; i < 4; ++i) {
        int q0 = (int)lrintf(f[i] * inv * s);
        int q1 = (int)lrintf(f[i + 4] * inv * s);
        lo |= (q0 & 255) << (8 * i);
        hi |= (q1 & 255) << (8 * i);
    }
    ((int2*)(Q + (size_t)row * HID))[lane] = make_int2(lo, hi);
    if (lane == 0) recip[row] = maxn * (1.f / 127.f);
}

// ---------------------------------------------------------------------------
// int8 similarity, SMALL-FOOTPRINT blocks for co-residency: 128x64 tile,
// 4 waves of 64x32 (acc 32 regs), BK=64, LDS 12 KB, launch_bounds(256,5)
// -> ~5 blocks (20 waves) per CU so the 4 pipes (MFMA / LDS / VMEM / VALU
// epilogue) overlap across blocks instead of serializing per wave.
// ---------------------------------------------------------------------------
__global__ __launch_bounds__(256, 5)
void gemm_sim(const char* __restrict__ Q1, const char* __restrict__ Q2,
              const float* __restrict__ recip,
              float* __restrict__ rowsum, float* __restrict__ colsum)
{
    __shared__ char ldsA[128 * 64];   // 8 KB
    __shared__ char ldsB[64 * 64];    // 4 KB
    const int tid = threadIdx.x;
    const int w = tid >> 6, lane = tid & 63;
    const int wm = w >> 1, wn = w & 1;
    const int quad = lane >> 4, r16 = lane & 15;
    const int bM = blockIdx.x * 128, bN = blockIdx.y * 64;
    const int lrow = lane >> 2, lcol = (lane & 3) * 16;   // bytes within 64B row

    i32x4 acc[4][2] = {};

    for (int k0 = 0; k0 < HID; k0 += 64) {
        __syncthreads();
        // A: 8 chunks of 16 rows, wave w stages chunks 2w, 2w+1
#pragma unroll
        for (int i = 0; i < 2; ++i) {
            int r0 = (w * 2 + i) * 16;
            gload_lds16(Q1 + (size_t)(bM + r0 + lrow) * HID + k0 + lcol, &ldsA[r0 * 64]);
        }
        // B: 4 chunks of 16 rows, wave w stages chunk w
        {
            int r0 = w * 16;
            gload_lds16(Q2 + (size_t)(bN + r0 + lrow) * HID + k0 + lcol, &ldsB[r0 * 64]);
        }
        __syncthreads();
        i32x4 af[4], bfr[2];
#pragma unroll
        for (int t = 0; t < 4; ++t)
            af[t] = *(const i32x4*)&ldsA[(wm * 64 + t * 16 + r16) * 64 + quad * 16];
#pragma unroll
        for (int t = 0; t < 2; ++t)
            bfr[t] = *(const i32x4*)&ldsB[(wn * 32 + t * 16 + r16) * 64 + quad * 16];
#pragma unroll
        for (int tm = 0; tm < 4; ++tm)
#pragma unroll
            for (int tn = 0; tn < 2; ++tn)
                acc[tm][tn] = __builtin_amdgcn_mfma_i32_16x16x64_i8(
                    af[tm], bfr[tn], acc[tm][tn], 0, 0, 0);
    }

    // epilogue: e = exp2(i32 * ra * cb), cb folds recip_col * TAU_INV * LOG2E
    float cb[2], cs[2] = {0.f, 0.f};
#pragma unroll
    for (int tn = 0; tn < 2; ++tn)
        cb[tn] = recip[NROWS + bN + wn * 32 + tn * 16 + r16] * (TAU_INV * LOG2E);

#pragma unroll
    for (int tm = 0; tm < 4; ++tm) {
#pragma unroll
        for (int r = 0; r < 4; ++r) {
            int grow = bM + wm * 64 + tm * 16 + quad * 4 + r;  // C/D: row=quad*4+reg
            float ra = recip[grow];
            float rs = 0.f;
#pragma unroll
            for (int tn = 0; tn < 2; ++tn) {
                float e = exp2f((float)acc[tm][tn][r] * ra * cb[tn]);
                rs += e;
                cs[tn] += e;
            }
#pragma unroll
            for (int m = 1; m < 16; m <<= 1) rs += __shfl_xor(rs, m, 64);
            if (r16 == 0) atomicAdd(&rowsum[grow], rs);
        }
    }
#pragma unroll
    for (int tn = 0; tn < 2; ++tn) {
        float c = cs[tn];
        c += __shfl_xor(c, 16, 64);
        c += __shfl_xor(c, 32, 64);
        if (quad == 0)
            atomicAdd(&colsum[bN + wn * 32 + tn * 16 + r16], c);
    }
}

// ---------------------------------------------------------------------------
// Edge numerators, one wave per node (edges are row-sorted, 8 per node):
// row fragments loaded once; exact int8 dots in float; direct store (no atomic).
// ---------------------------------------------------------------------------
__global__ void edge_kernel(const char* __restrict__ Q1, const char* __restrict__ Q2,
                            const float* __restrict__ recip, const int* __restrict__ pos,
                            float* __restrict__ smp, float* __restrict__ ssc, int E)
{
    int row = blockIdx.x * (blockDim.x >> 6) + (threadIdx.x >> 6);
    int lane = threadIdx.x & 63;
    if (row >= NROWS) return;
    int2 a1 = ((const int2*)(Q1 + (size_t)row * HID))[lane];
    int2 a2 = ((const int2*)(Q2 + (size_t)row * HID))[lane];
    float s1 = 0.f, s2 = 0.f;
    float ir1 = recip[row], ir2 = recip[NROWS + row];
#pragma unroll
    for (int e = 0; e < 8; ++e) {
        int c = pos[E + row * 8 + e];
        int2 b2 = ((const int2*)(Q2 + (size_t)c * HID))[lane];
        int2 b1 = ((const int2*)(Q1 + (size_t)c * HID))[lane];
        float d1 = (float)(dot4i(a1.x, b2.x) + dot4i(a1.y, b2.y));
        float d2 = (float)(dot4i(b1.x, a2.x) + dot4i(b1.y, a2.y));
#pragma unroll
        for (int m = 1; m < 64; m <<= 1) {
            d1 += __shfl_xor(d1, m, 64);
            d2 += __shfl_xor(d2, m, 64);
        }
        if (lane == 0) {
            s1 += __expf(d1 * ir1 * recip[NROWS + c] * TAU_INV);   // S[row,c]
            s2 += __expf(d2 * recip[c] * ir2 * TAU_INV);           // S[c,row]
        }
    }
    if (lane == 0) { smp[row] = s1; ssc[row] = s2; }
}

// Single-block finalize (1024 threads): loss = mean over rows -> out[0].
__global__ void finalize(const float* __restrict__ rowsum, const float* __restrict__ colsum,
                         const float* __restrict__ smp, const float* __restrict__ ssc,
                         float* __restrict__ out, int n)
{
    float contrib = 0.f;
    for (int i = threadIdx.x; i < n; i += blockDim.x) {
        float t = (smp[i] / rowsum[i]) * (ssc[i] / colsum[i]);
        contrib += -0.5f * logf(t) / (float)n;
    }
#pragma unroll
    for (int m = 1; m < 64; m <<= 1) contrib += __shfl_xor(contrib, m, 64);
    __shared__ float wsum[16];
    int w = threadIdx.x >> 6, lane = threadIdx.x & 63;
    if (lane == 0) wsum[w] = contrib;
    __syncthreads();
    if (threadIdx.x == 0) {
        float s = 0.f;
#pragma unroll
        for (int i = 0; i < 16; ++i) s += wsum[i];
        out[0] = s;
    }
}

extern "C" void kernel_launch(void* const* d_in, const int* in_sizes, int n_in,
                              void* d_out, int out_size, void* d_ws, size_t ws_size,
                              hipStream_t stream)
{
    const float* z_mp = (const float*)d_in[0];
    const float* z_sc = (const float*)d_in[1];
    const float* W1f  = (const float*)d_in[2];
    const float* b1   = (const float*)d_in[3];
    const float* W2f  = (const float*)d_in[4];
    const float* b2   = (const float*)d_in[5];
    const int*   pos  = (const int*)d_in[6];
    const int E = in_sizes[6] / 2;
    const int ZN = NROWS * HID;       // 4M elems
    const int WN = HID * HID;         // 256K elems

    // workspace layout (~34 MB):
    //   [0,16MB)   : Zb_mp, Zb_sc (bf16) -> dead after proj1 -> reused as P1,P2
    //   [16,32MB)  : H1,H2 (bf16) -> dead after proj2 -> reused as Q (int8, 8MB)
    //   [32MB,..)  : Wb1, Wb2, rowsum, colsum, recip(64KB), smp, ssc
    char* ws = (char*)d_ws;
    short* Zb1 = (short*)ws;
    short* Zb2 = Zb1 + ZN;
    short* P1  = Zb1;                 // alias: Zb dead after proj1
    short* P2  = Zb2;
    short* H1  = (short*)(ws + (size_t)16 * 1024 * 1024);
    short* H2  = H1 + ZN;
    char*  Q   = (char*)H1;           // alias: H dead after proj2; 2*NROWS rows
    char*  Q1  = Q;
    char*  Q2  = Q + (size_t)NROWS * HID;
    short* Wb1 = (short*)(ws + (size_t)32 * 1024 * 1024);
    short* Wb2 = Wb1 + WN;
    float* rowsum = (float*)(Wb2 + WN);
    float* colsum = rowsum + NROWS;
    float* recip  = colsum + NROWS;   // 2*NROWS floats
    float* smp    = recip + 2 * NROWS;
    float* ssc    = smp + NROWS;

    dim3 blk(256);
    // fp32 -> bf16 conversions + rowsum/colsum zeroing (single launch)
    convert_all<<<dim3((2 * ZN + 2 * WN) / 1024 + 16), blk, 0, stream>>>(
        z_mp, z_sc, W1f, W2f, Zb1, Zb2, Wb1, Wb2, rowsum);
    // H = elu(Z @ W1^T + b1) for both inputs (grid.z)
    gemm_proj<<<dim3(64, 4, 2), blk, 0, stream>>>(Zb1, Zb2, Wb1, b1, H1, H2, 1);
    // P = H @ W2^T + b2   (P overwrites Zb region — Zb dead now)
    gemm_proj<<<dim3(64, 4, 2), blk, 0, stream>>>(H1, H2, Wb2, b2, P1, P2, 0);
    // normalize + int8 quantize both P1,P2 (2*NROWS contiguous rows) -> Q, recip
    normalize_quant<<<dim3((2 * NROWS) / 4), blk, 0, stream>>>(P1, Q, recip, 2 * NROWS);
    // rowsum/colsum via i8 MFMA, small 128x64 tiles for 5-block co-residency
    gemm_sim<<<dim3(64, 128), blk, 0, stream>>>(Q1, Q2, recip, rowsum, colsum);
    // per-edge numerators, one wave per node, direct store
    edge_kernel<<<dim3(NROWS / 4), blk, 0, stream>>>(Q1, Q2, recip, pos, smp, ssc, E);
    // single-block reduce straight into d_out
    finalize<<<dim3(1), dim3(1024), 0, stream>>>(rowsum, colsum, smp, ssc, (float*)d_out, NROWS);
}

// Round 12
// 239.062 us; speedup vs baseline: 1.0966x; 1.0195x over previous
//
#include <hip/hip_runtime.h>

typedef __attribute__((ext_vector_type(8))) short s16x8;   // 8 bf16
typedef __attribute__((ext_vector_type(4))) float f32x4;
typedef __attribute__((ext_vector_type(4))) int   i32x4;

#define HID 512
#define NROWS 8192
#define TAU_INV 1.25f
#define LOG2E 1.4426950408889634f

__device__ __forceinline__ float bf2f(short s) {
    union { unsigned u; float f; } v;
    v.u = ((unsigned)(unsigned short)s) << 16;
    return v.f;
}
__device__ __forceinline__ short f2bf(float f) {
    unsigned u = __float_as_uint(f);
    u += 0x7fffu + ((u >> 16) & 1u);   // round-to-nearest-even
    return (short)(u >> 16);
}

__device__ __forceinline__ void gload_lds16(const void* g, void* l) {
    __builtin_amdgcn_global_load_lds(
        (const __attribute__((address_space(1))) unsigned int*)g,
        (__attribute__((address_space(3))) unsigned int*)l, 16, 0, 0);
}

__device__ __forceinline__ int dot4i(int a, int b) {
    int s = 0;
#pragma unroll
    for (int i = 0; i < 4; ++i)
        s += (int)(signed char)(a >> (8 * i)) * (int)(signed char)(b >> (8 * i));
    return s;
}

// ---------------------------------------------------------------------------
// Fused fp32->bf16 convert for z_mp, z_sc, W1, W2 + zeroing of rowsum/colsum
// (tail blocks), all in one launch.
// ---------------------------------------------------------------------------
__global__ void convert_all(const float* __restrict__ z1, const float* __restrict__ z2,
                            const float* __restrict__ w1, const float* __restrict__ w2,
                            short* __restrict__ Zb1, short* __restrict__ Zb2,
                            short* __restrict__ Wb1, short* __restrict__ Wb2,
                            float* __restrict__ zsum)
{
    const int ZN = NROWS * HID, WN = HID * HID;
    const int NCONV = (2 * ZN + 2 * WN) / 1024;   // conversion blocks
    if ((int)blockIdx.x >= NCONV) {               // tail: zero rowsum+colsum
        int zi = ((int)blockIdx.x - NCONV) * 1024 + threadIdx.x * 4;
        if (zi < 2 * NROWS)
            *(float4*)(zsum + zi) = make_float4(0.f, 0.f, 0.f, 0.f);
        return;
    }
    long i = (long)(blockIdx.x * blockDim.x + threadIdx.x) * 4;
    const float* src;
    short* dst;
    long off;
    if (i < ZN)                { src = z1; dst = Zb1; off = i; }
    else if (i < 2L * ZN)      { src = z2; dst = Zb2; off = i - ZN; }
    else if (i < 2L * ZN + WN) { src = w1; dst = Wb1; off = i - 2L * ZN; }
    else                       { src = w2; dst = Wb2; off = i - 2L * ZN - WN; }
    float4 v = *(const float4*)(src + off);
    short4 o;
    o.x = f2bf(v.x); o.y = f2bf(v.y); o.z = f2bf(v.z); o.w = f2bf(v.w);
    *(short4*)(dst + off) = o;
}

// ---------------------------------------------------------------------------
// bf16 NT GEMM, 64x128 tile (1024 blocks -> ~4/CU vs old 2/CU): more
// co-resident blocks to overlap the per-iter barrier drains. XOR source
// swizzle (R10-verified) keeps ds_read conflict-free; staging VMEM pattern
// unchanged (each quarter-wave still reads 64 contiguous bytes of one row).
// 4 waves of 32x64 (2x4 mfma_f32_16x16x32_bf16, acc 32 VGPR).
// ---------------------------------------------------------------------------
__global__ __launch_bounds__(256, 4)
void gemm_proj(const short* __restrict__ A0, const short* __restrict__ A1,
               const short* __restrict__ B, const float* __restrict__ bias,
               short* __restrict__ C0, short* __restrict__ C1, int do_elu)
{
    __shared__ short ldsA[64 * 32];    // 4 KB
    __shared__ short ldsB[128 * 32];   // 8 KB
    const short* A = blockIdx.z ? A1 : A0;
    short* C = blockIdx.z ? C1 : C0;
    const int tid = threadIdx.x;
    const int w = tid >> 6, lane = tid & 63;
    const int wm = w & 1, wn = w >> 1;
    const int quad = lane >> 4, r16 = lane & 15;
    const int bM = blockIdx.x * 64, bN = blockIdx.y * 128;
    const int lrow = lane >> 2;
    const int lq   = ((lane & 3) ^ ((lane >> 3) & 3)) * 8;   // swizzled src slot (shorts)
    const int aswz = (quad ^ ((r16 >> 1) & 3)) * 8;          // swizzled read slot (shorts)

    f32x4 acc[2][4] = {};

    for (int k0 = 0; k0 < HID; k0 += 32) {
        __syncthreads();
        {   // A: 4 chunks of 16 rows, one per wave
            int r0 = w * 16;
            gload_lds16(A + (size_t)(bM + r0 + lrow) * HID + k0 + lq, &ldsA[r0 * 32]);
        }
#pragma unroll
        for (int i = 0; i < 2; ++i) {   // B: 8 chunks, two per wave
            int r0 = (w * 2 + i) * 16;
            gload_lds16(B + (size_t)(bN + r0 + lrow) * HID + k0 + lq, &ldsB[r0 * 32]);
        }
        __syncthreads();
        s16x8 af[2], bfr[4];
#pragma unroll
        for (int t = 0; t < 2; ++t)
            af[t]  = *(const s16x8*)&ldsA[(wm * 32 + t * 16 + r16) * 32 + aswz];
#pragma unroll
        for (int t = 0; t < 4; ++t)
            bfr[t] = *(const s16x8*)&ldsB[(wn * 64 + t * 16 + r16) * 32 + aswz];
#pragma unroll
        for (int tm = 0; tm < 2; ++tm)
#pragma unroll
            for (int tn = 0; tn < 4; ++tn)
                acc[tm][tn] = __builtin_amdgcn_mfma_f32_16x16x32_bf16(
                    af[tm], bfr[tn], acc[tm][tn], 0, 0, 0);
    }

#pragma unroll
    for (int tn = 0; tn < 4; ++tn) {
        int gcol = bN + wn * 64 + tn * 16 + r16;
        float bv = bias[gcol];
#pragma unroll
        for (int tm = 0; tm < 2; ++tm) {
#pragma unroll
            for (int r = 0; r < 4; ++r) {
                int grow = bM + wm * 32 + tm * 16 + quad * 4 + r;  // C/D: row=(lane>>4)*4+reg
                float v = acc[tm][tn][r] + bv;
                if (do_elu) v = v > 0.f ? v : __expf(v) - 1.f;
                C[(size_t)grow * HID + gcol] = f2bf(v);
            }
        }
    }
}

// ---------------------------------------------------------------------------
// normalize + int8 row-quantize: q = round(n * 127/max|n_row|), one wave/row.
// recip[row] = max|n_row|/127, so dot_real = i32acc * recip[r] * recip[c].
// ---------------------------------------------------------------------------
__global__ void normalize_quant(const short* __restrict__ P, char* __restrict__ Q,
                                float* __restrict__ recip, int nrows)
{
    int gt = blockIdx.x * blockDim.x + threadIdx.x;
    int row = gt >> 6, lane = gt & 63;
    if (row >= nrows) return;
    const short* p = P + (size_t)row * HID + lane * 8;
    s16x8 v = *(const s16x8*)p;
    float f[8], ss = 0.f, am = 0.f;
#pragma unroll
    for (int i = 0; i < 8; ++i) {
        f[i] = bf2f(v[i]);
        ss += f[i] * f[i];
        am = fmaxf(am, fabsf(f[i]));
    }
#pragma unroll
    for (int m = 1; m < 64; m <<= 1) {
        ss += __shfl_xor(ss, m, 64);
        am = fmaxf(am, __shfl_xor(am, m, 64));
    }
    float inv = rsqrtf(ss);
    float maxn = am * inv;             // max |n_i| over the row
    float s = 127.f / maxn;
    int lo = 0, hi = 0;
#pragma unroll
    for (int i = 0; i < 4; ++i) {
        int q0 = (int)lrintf(f[i] * inv * s);
        int q1 = (int)lrintf(f[i + 4] * inv * s);
        lo |= (q0 & 255) << (8 * i);
        hi |= (q1 & 255) << (8 * i);
    }
    ((int2*)(Q + (size_t)row * HID))[lane] = make_int2(lo, hi);
    if (lane == 0) recip[row] = maxn * (1.f / 127.f);
}

// ---------------------------------------------------------------------------
// int8 similarity — R7 structure (best measured: 100.6 us) + XOR swizzle
// (R10-verified: 0 bank conflicts, VMEM-neutral) + launch_bounds(256,3)
// (VGPR ~136 -> 3 blocks/CU vs R7's 2) + exp2 fold (cb absorbs TAU_INV*LOG2E).
// 128x128 tile, BK=64, 4 waves of 64x64 (4x4 mfma_i32_16x16x64_i8).
// ---------------------------------------------------------------------------
__global__ __launch_bounds__(256, 3)
void gemm_sim(const char* __restrict__ Q1, const char* __restrict__ Q2,
              const float* __restrict__ recip,
              float* __restrict__ rowsum, float* __restrict__ colsum)
{
    __shared__ char ldsA[128 * 64];   // 8 KB
    __shared__ char ldsB[128 * 64];   // 8 KB
    const int tid = threadIdx.x;
    const int w = tid >> 6, lane = tid & 63;
    const int wm = w >> 1, wn = w & 1;
    const int quad = lane >> 4, r16 = lane & 15;
    const int bM = blockIdx.x * 128, bN = blockIdx.y * 128;
    const int lrow = lane >> 2;
    const int lq   = ((lane & 3) ^ ((lane >> 3) & 3)) * 16;  // swizzled src slot (bytes)
    const int aswz = (quad ^ ((r16 >> 1) & 3)) * 16;         // swizzled read slot (bytes)

    i32x4 acc[4][4] = {};

    for (int k0 = 0; k0 < HID; k0 += 64) {
        __syncthreads();
#pragma unroll
        for (int i = 0; i < 2; ++i) {
            int r0 = (w * 2 + i) * 16;
            gload_lds16(Q1 + (size_t)(bM + r0 + lrow) * HID + k0 + lq, &ldsA[r0 * 64]);
            gload_lds16(Q2 + (size_t)(bN + r0 + lrow) * HID + k0 + lq, &ldsB[r0 * 64]);
        }
        __syncthreads();
        i32x4 af[4], bfr[4];
#pragma unroll
        for (int t = 0; t < 4; ++t) {
            af[t]  = *(const i32x4*)&ldsA[(wm * 64 + t * 16 + r16) * 64 + aswz];
            bfr[t] = *(const i32x4*)&ldsB[(wn * 64 + t * 16 + r16) * 64 + aswz];
        }
#pragma unroll
        for (int tm = 0; tm < 4; ++tm)
#pragma unroll
            for (int tn = 0; tn < 4; ++tn)
                acc[tm][tn] = __builtin_amdgcn_mfma_i32_16x16x64_i8(
                    af[tm], bfr[tn], acc[tm][tn], 0, 0, 0);
    }

    // epilogue: e = exp2(i32 * ra * cb); cb folds recip_col * TAU_INV * LOG2E
    float cb[4], cs[4] = {0.f, 0.f, 0.f, 0.f};
#pragma unroll
    for (int tn = 0; tn < 4; ++tn)
        cb[tn] = recip[NROWS + bN + wn * 64 + tn * 16 + r16] * (TAU_INV * LOG2E);

#pragma unroll
    for (int tm = 0; tm < 4; ++tm) {
#pragma unroll
        for (int r = 0; r < 4; ++r) {
            int grow = bM + wm * 64 + tm * 16 + quad * 4 + r;  // C/D: row=quad*4+reg
            float ra = recip[grow];
            float rs = 0.f;
#pragma unroll
            for (int tn = 0; tn < 4; ++tn) {
                float e = exp2f((float)acc[tm][tn][r] * ra * cb[tn]);
                rs += e;
                cs[tn] += e;
            }
#pragma unroll
            for (int m = 1; m < 16; m <<= 1) rs += __shfl_xor(rs, m, 64);
            if (r16 == 0) atomicAdd(&rowsum[grow], rs);
        }
    }
#pragma unroll
    for (int tn = 0; tn < 4; ++tn) {
        float c = cs[tn];
        c += __shfl_xor(c, 16, 64);
        c += __shfl_xor(c, 32, 64);
        if (quad == 0)
            atomicAdd(&colsum[bN + wn * 64 + tn * 16 + r16], c);
    }
}

// ---------------------------------------------------------------------------
// Edge numerators, one wave per node (edges are row-sorted, 8 per node):
// row fragments loaded once; exact int8 dots in float; direct store (no atomic).
// ---------------------------------------------------------------------------
__global__ void edge_kernel(const char* __restrict__ Q1, const char* __restrict__ Q2,
                            const float* __restrict__ recip, const int* __restrict__ pos,
                            float* __restrict__ smp, float* __restrict__ ssc, int E)
{
    int row = blockIdx.x * (blockDim.x >> 6) + (threadIdx.x >> 6);
    int lane = threadIdx.x & 63;
    if (row >= NROWS) return;
    int2 a1 = ((const int2*)(Q1 + (size_t)row * HID))[lane];
    int2 a2 = ((const int2*)(Q2 + (size_t)row * HID))[lane];
    float s1 = 0.f, s2 = 0.f;
    float ir1 = recip[row], ir2 = recip[NROWS + row];
#pragma unroll
    for (int e = 0; e < 8; ++e) {
        int c = pos[E + row * 8 + e];
        int2 b2 = ((const int2*)(Q2 + (size_t)c * HID))[lane];
        int2 b1 = ((const int2*)(Q1 + (size_t)c * HID))[lane];
        float d1 = (float)(dot4i(a1.x, b2.x) + dot4i(a1.y, b2.y));
        float d2 = (float)(dot4i(b1.x, a2.x) + dot4i(b1.y, a2.y));
#pragma unroll
        for (int m = 1; m < 64; m <<= 1) {
            d1 += __shfl_xor(d1, m, 64);
            d2 += __shfl_xor(d2, m, 64);
        }
        if (lane == 0) {
            s1 += __expf(d1 * ir1 * recip[NROWS + c] * TAU_INV);   // S[row,c]
            s2 += __expf(d2 * recip[c] * ir2 * TAU_INV);           // S[c,row]
        }
    }
    if (lane == 0) { smp[row] = s1; ssc[row] = s2; }
}

// Single-block finalize (1024 threads): loss = mean over rows -> out[0].
__global__ void finalize(const float* __restrict__ rowsum, const float* __restrict__ colsum,
                         const float* __restrict__ smp, const float* __restrict__ ssc,
                         float* __restrict__ out, int n)
{
    float contrib = 0.f;
    for (int i = threadIdx.x; i < n; i += blockDim.x) {
        float t = (smp[i] / rowsum[i]) * (ssc[i] / colsum[i]);
        contrib += -0.5f * logf(t) / (float)n;
    }
#pragma unroll
    for (int m = 1; m < 64; m <<= 1) contrib += __shfl_xor(contrib, m, 64);
    __shared__ float wsum[16];
    int w = threadIdx.x >> 6, lane = threadIdx.x & 63;
    if (lane == 0) wsum[w] = contrib;
    __syncthreads();
    if (threadIdx.x == 0) {
        float s = 0.f;
#pragma unroll
        for (int i = 0; i < 16; ++i) s += wsum[i];
        out[0] = s;
    }
}

extern "C" void kernel_launch(void* const* d_in, const int* in_sizes, int n_in,
                              void* d_out, int out_size, void* d_ws, size_t ws_size,
                              hipStream_t stream)
{
    const float* z_mp = (const float*)d_in[0];
    const float* z_sc = (const float*)d_in[1];
    const float* W1f  = (const float*)d_in[2];
    const float* b1   = (const float*)d_in[3];
    const float* W2f  = (const float*)d_in[4];
    const float* b2   = (const float*)d_in[5];
    const int*   pos  = (const int*)d_in[6];
    const int E = in_sizes[6] / 2;
    const int ZN = NROWS * HID;       // 4M elems
    const int WN = HID * HID;         // 256K elems

    // workspace layout (~34 MB):
    //   [0,16MB)   : Zb_mp, Zb_sc (bf16) -> dead after proj1 -> reused as P1,P2
    //   [16,32MB)  : H1,H2 (bf16) -> dead after proj2 -> reused as Q (int8, 8MB)
    //   [32MB,..)  : Wb1, Wb2, rowsum, colsum, recip(64KB), smp, ssc
    char* ws = (char*)d_ws;
    short* Zb1 = (short*)ws;
    short* Zb2 = Zb1 + ZN;
    short* P1  = Zb1;                 // alias: Zb dead after proj1
    short* P2  = Zb2;
    short* H1  = (short*)(ws + (size_t)16 * 1024 * 1024);
    short* H2  = H1 + ZN;
    char*  Q   = (char*)H1;           // alias: H dead after proj2; 2*NROWS rows
    char*  Q1  = Q;
    char*  Q2  = Q + (size_t)NROWS * HID;
    short* Wb1 = (short*)(ws + (size_t)32 * 1024 * 1024);
    short* Wb2 = Wb1 + WN;
    float* rowsum = (float*)(Wb2 + WN);
    float* colsum = rowsum + NROWS;
    float* recip  = colsum + NROWS;   // 2*NROWS floats
    float* smp    = recip + 2 * NROWS;
    float* ssc    = smp + NROWS;

    dim3 blk(256);
    // fp32 -> bf16 conversions + rowsum/colsum zeroing (single launch)
    convert_all<<<dim3((2 * ZN + 2 * WN) / 1024 + 16), blk, 0, stream>>>(
        z_mp, z_sc, W1f, W2f, Zb1, Zb2, Wb1, Wb2, rowsum);
    // H = elu(Z @ W1^T + b1) for both inputs (grid.z); 64x128 tiles, 1024 blocks
    gemm_proj<<<dim3(128, 4, 2), blk, 0, stream>>>(Zb1, Zb2, Wb1, b1, H1, H2, 1);
    // P = H @ W2^T + b2   (P overwrites Zb region — Zb dead now)
    gemm_proj<<<dim3(128, 4, 2), blk, 0, stream>>>(H1, H2, Wb2, b2, P1, P2, 0);
    // normalize + int8 quantize both P1,P2 (2*NROWS contiguous rows) -> Q, recip
    normalize_quant<<<dim3((2 * NROWS) / 4), blk, 0, stream>>>(P1, Q, recip, 2 * NROWS);
    // rowsum/colsum via i8 MFMA, 128x128 tiles + swizzle + 3 blocks/CU
    gemm_sim<<<dim3(64, 64), blk, 0, stream>>>(Q1, Q2, recip, rowsum, colsum);
    // per-edge numerators, one wave per node, direct store
    edge_kernel<<<dim3(NROWS / 4), blk, 0, stream>>>(Q1, Q2, recip, pos, smp, ssc, E);
    // single-block reduce straight into d_out
    finalize<<<dim3(1), dim3(1024), 0, stream>>>(rowsum, colsum, smp, ssc, (float*)d_out, NROWS);
}